// Round 1
// baseline (149.422 us; speedup 1.0000x reference)
//
#include <hip/hip_runtime.h>
#include <cfloat>
#include <cmath>

#define DIM 64
#define TT 2048
#define NTOT 65536
#define KE 1024

typedef _Float16 f16x8 __attribute__((ext_vector_type(8)));
typedef _Float16 f16x4 __attribute__((ext_vector_type(4)));
typedef float    f32x4 __attribute__((ext_vector_type(4)));

// ws layout (bytes):
//   planes [0, 262144)      : fp16 hi plane (131072 B) + fp16 lo plane (131072 B)
//   e2     [262144, 266240) : 1024 f32
// plane vector layout (B-fragment-ready, verified R5/R6): f16x8 index
//   ((g*2+k)*64 + l) for group g (16 codes), kstep k, lane l=q*16+ln holding
//   embed_plane[c=g*16+ln][j=k*32+q*8 .. +7].
#define WS_NEED 266240

// async global->LDS, 16B per lane; LDS dest is wave-uniform base + lane*16
__device__ __forceinline__ void gload_lds16(const void* g, void* l) {
    __builtin_amdgcn_global_load_lds(
        (const __attribute__((address_space(1))) unsigned int*)g,
        (__attribute__((address_space(3))) unsigned int*)l, 16, 0, 0);
}

// ============================ fast path ====================================
__global__ __launch_bounds__(256) void prep_kernel(
    const float* __restrict__ embed,
    _Float16* __restrict__ planes,
    float* __restrict__ e2g,
    float* __restrict__ counts,        // out_avg region  (zeroed here)
    float* __restrict__ distsum)       // out_commit slot (zeroed here)
{
    const int gidx = blockIdx.x * 256 + threadIdx.x;   // 8192 threads
    const int g  = gidx >> 7;
    const int k  = (gidx >> 6) & 1;
    const int l  = gidx & 63;
    const int q  = l >> 4;
    const int ln = l & 15;
    const int c  = g * 16 + ln;
    const int jb = k * 32 + q * 8;

    const float4 v0 = *(const float4*)(embed + (size_t)c * DIM + jb);
    const float4 v1 = *(const float4*)(embed + (size_t)c * DIM + jb + 4);
    const float xf[8] = {v0.x, v0.y, v0.z, v0.w, v1.x, v1.y, v1.z, v1.w};
    f16x8 h1, h2;
    #pragma unroll
    for (int e = 0; e < 8; ++e) {
        const _Float16 a = (_Float16)xf[e];
        h1[e] = a;
        h2[e] = (_Float16)(xf[e] - (float)a);   // exact residual
    }
    const int off = ((g * 2 + k) * 64 + l) * 8;
    *(f16x8*)(planes + off)         = h1;
    *(f16x8*)(planes + 65536 + off) = h2;

    if (gidx < KE) {
        const float4* rp = (const float4*)(embed + (size_t)gidx * DIM);
        float s = 0.f;
        #pragma unroll
        for (int i = 0; i < 16; ++i) {
            const float4 v = rp[i];
            s += v.x * v.x + v.y * v.y + v.z * v.z + v.w * v.w;
        }
        e2g[gidx]    = s;
        counts[gidx] = 0.f;
        if (gidx == 0) distsum[0] = 0.f;
    }
}

// Fused full-K argmin + gather. Grid 1024 = one block per 64 t, all 1024
// codes per block (so the argmin is block-local and exact -> no keys pass).
// B-planes staged 2 groups (8KB) at a time into double-buffered LDS via
// global_load_lds (m97 pattern): L2 streaming cut 4x (one read per block,
// not per wave) and load latency hidden behind the MFMA phase.
// Numerics identical to the verified R5/R6 kernel: same planes, same A
// fragments, same 8-MFMA accumulation order, strict < + ascending index.
__global__ __launch_bounds__(256, 4) void argmin_fused(
    const float* __restrict__ x,       // [B][D][T]
    const _Float16* __restrict__ P,    // ws planes (hi at +0, lo at +131072 B)
    const float* __restrict__ e2g,     // ws e2
    const float* __restrict__ embed,
    float* __restrict__ out_q,
    float* __restrict__ out_idx,
    float* __restrict__ counts,
    float* __restrict__ distsum)
{
    // bbuf: 2 buffers x 2 groups x 4KB. slot layout per group:
    //   [k0 plane1 | k1 plane1 | k0 plane2 | k1 plane2], 1KB each,
    //   lane l's f16x8 at byte l*16 within its 1KB quarter.
    __shared__ __align__(16) _Float16 bbuf[2][4096];
    __shared__ float e2s[1024];
    __shared__ int   ibest[64];
    __shared__ float x2s[64];
    __shared__ float mdsum[1];

    const int tid = threadIdx.x;
    const int l   = tid & 63;
    const int w   = tid >> 6;
    const int q   = l >> 4;
    const int ln  = l & 15;
    const int n0  = blockIdx.x << 6;   // global t index base
    const int b   = n0 >> 11;          // TT = 2048
    const int t0  = n0 & 2047;

    if (tid == 0) mdsum[0] = 0.f;
    *(float4*)&e2s[tid * 4] = *(const float4*)(e2g + tid * 4);

    const char* Pb = (const char*)P;
    // stage group g into buffer bi, slot s (wave w covers one 1KB quarter)
#define STAGE(bi, gg, ss)                                                     \
    gload_lds16(Pb + ((w < 2) ? 0 : 131072) + (gg) * 2048 + (w & 1) * 1024 +  \
                    l * 16,                                                   \
                (void*)&bbuf[bi][(ss) * 2048 + w * 512])

    // ---- A fragments: fp16 split in registers (layout verified R5/R6) ----
    // t = t0 + w*16 + ln, j = k*32 + q*8 + jj
    f16x8 af[2][2];                    // [plane][k]
    float x2p = 0.f;
    #pragma unroll
    for (int k = 0; k < 2; ++k)
        #pragma unroll
        for (int jj = 0; jj < 8; ++jj) {
            const int j = k * 32 + q * 8 + jj;
            const float xf = x[(size_t)(b * DIM + j) * TT + t0 + w * 16 + ln];
            const _Float16 h1 = (_Float16)xf;
            af[0][k][jj] = h1;
            af[1][k][jj] = (_Float16)(xf - (float)h1);
            x2p = fmaf(xf, xf, x2p);
        }
    // full ||x_t||^2: sum the 4 q-quarters (lanes with same ln)
    x2p += __shfl_xor(x2p, 16);
    x2p += __shfl_xor(x2p, 32);
    if (q == 0) x2s[w * 16 + ln] = x2p;

    STAGE(0, 0, 0);
    STAGE(0, 1, 1);
    __syncthreads();                   // e2s, x2s, bbuf[0] ready

    float bs[4];
    int   bi_[4];
    #pragma unroll
    for (int r = 0; r < 4; ++r) { bs[r] = FLT_MAX; bi_[r] = 0; }

    // ---- hot loop: 32 iters x 2 groups of 16 codes, all 1024 codes ----
    for (int it = 0; it < 32; ++it) {
        const int cur = it & 1;
        if (it < 31) {                 // async prefetch next 2 groups
            STAGE(cur ^ 1, it * 2 + 2, 0);
            STAGE(cur ^ 1, it * 2 + 3, 1);
        }
        #pragma unroll
        for (int gs = 0; gs < 2; ++gs) {
            const _Float16* bp = &bbuf[cur][gs * 2048];
            const f16x8 b1k0 = *(const f16x8*)(bp + l * 8);
            const f16x8 b1k1 = *(const f16x8*)(bp + 512 + l * 8);
            const f16x8 b2k0 = *(const f16x8*)(bp + 1024 + l * 8);
            const f16x8 b2k1 = *(const f16x8*)(bp + 1536 + l * 8);
            const int   cgl  = (it * 2 + gs) * 16 + ln;
            const float e2c  = e2s[cgl];
            f32x4 C = {0.f, 0.f, 0.f, 0.f};
            // small terms first for accuracy (verified R5/R6 ordering)
            C = __builtin_amdgcn_mfma_f32_16x16x32_f16(af[1][0], b2k0, C, 0, 0, 0);
            C = __builtin_amdgcn_mfma_f32_16x16x32_f16(af[1][1], b2k1, C, 0, 0, 0);
            C = __builtin_amdgcn_mfma_f32_16x16x32_f16(af[1][0], b1k0, C, 0, 0, 0);
            C = __builtin_amdgcn_mfma_f32_16x16x32_f16(af[1][1], b1k1, C, 0, 0, 0);
            C = __builtin_amdgcn_mfma_f32_16x16x32_f16(af[0][0], b2k0, C, 0, 0, 0);
            C = __builtin_amdgcn_mfma_f32_16x16x32_f16(af[0][1], b2k1, C, 0, 0, 0);
            C = __builtin_amdgcn_mfma_f32_16x16x32_f16(af[0][0], b1k0, C, 0, 0, 0);
            C = __builtin_amdgcn_mfma_f32_16x16x32_f16(af[0][1], b1k1, C, 0, 0, 0);
            #pragma unroll
            for (int r = 0; r < 4; ++r) {
                const float s = fmaf(-2.f, C[r], e2c);
                // strict < + ascending c keeps lowest index on ties
                if (s < bs[r]) { bs[r] = s; bi_[r] = cgl; }
            }
        }
        __syncthreads();               // drains prefetch; buf swap safe
    }

    // ---- reduce over the 16 code-columns; block-local result is final ----
    float mdloc = 0.f;
    #pragma unroll
    for (int r = 0; r < 4; ++r) {
        float s = bs[r]; int i = bi_[r];
        #pragma unroll
        for (int mask = 1; mask < 16; mask <<= 1) {
            const float s2 = __shfl_xor(s, mask);
            const int   i2 = __shfl_xor(i, mask);
            if (s2 < s || (s2 == s && i2 < i)) { s = s2; i = i2; }
        }
        if (ln == 0) {
            const int t_loc = w * 16 + q * 4 + r;   // C-row map (verified)
            ibest[t_loc] = i;
            out_idx[n0 + t_loc] = (float)i;
            atomicAdd(&counts[i], 1.0f);
            mdloc += x2s[t_loc] + s;                // ||x||^2 + e^2 - 2 x.e
        }
    }
    if (ln == 0) atomicAdd(&mdsum[0], mdloc);
    __syncthreads();
    if (tid == 0) atomicAdd(distsum, mdsum[0]);

    // ---- gather: out_q[b][j][t0+tt] = embed[ibest[tt]][j] (embed L2-hot) ---
    #pragma unroll
    for (int p = 0; p < 16; ++p) {
        const int f  = p * 256 + tid;
        const int j  = f >> 6;
        const int tt = f & 63;
        out_q[(size_t)(b * DIM + j) * TT + t0 + tt] =
            embed[(size_t)ibest[tt] * DIM + j];
    }
#undef STAGE
}

// ======================= fallback path (Round-5, passed) ====================
#define EP_ROW   72
#define EP_PLANE 4608
#define SMEM_BYTES (36864 + 4096 + 512 + 512 + 16)

__global__ __launch_bounds__(256, 2) void argmin_fb(
    const float* __restrict__ x, const float* __restrict__ embed,
    float* __restrict__ out_q, float* __restrict__ out_idx,
    float* __restrict__ counts, float* __restrict__ distsum)
{
    __shared__ __align__(16) char smem[SMEM_BYTES];
    _Float16* ep  = (_Float16*)smem;
    float* e2s    = (float*)(smem + 36864);
    float* x2s    = (float*)(smem + 36864 + 4096);
    int*   ibest  = (int*)  (smem + 36864 + 4608);
    float* mdsum  = (float*)(smem + 36864 + 5120);

    const int tid = threadIdx.x;
    const int l   = tid & 63;
    const int w   = tid >> 6;
    const int q   = l >> 4;
    const int ln  = l & 15;
    const int bid = blockIdx.x;
    const int b   = bid >> 4;
    const int t0  = (bid & 15) << 7;

    if (tid == 0) mdsum[0] = 0.f;
    #pragma unroll
    for (int pass = 0; pass < 4; ++pass) {
        const int c = pass * 256 + tid;
        const float4* rp = (const float4*)(embed + (size_t)c * DIM);
        float s = 0.f;
        #pragma unroll
        for (int i = 0; i < 16; ++i) {
            const float4 v = rp[i];
            s += v.x * v.x + v.y * v.y + v.z * v.z + v.w * v.w;
        }
        e2s[c] = s;
    }
    f16x8 af[2][2][2];
    float x2p[2] = {0.f, 0.f};
    #pragma unroll
    for (int m = 0; m < 2; ++m)
        #pragma unroll
        for (int k = 0; k < 2; ++k)
            #pragma unroll
            for (int jj = 0; jj < 8; ++jj) {
                const int j = k * 32 + q * 8 + jj;
                const float xf = x[(size_t)(b * DIM + j) * TT + t0 + w * 32 + m * 16 + ln];
                const _Float16 h1 = (_Float16)xf;
                af[0][m][k][jj] = h1;
                af[1][m][k][jj] = (_Float16)(xf - (float)h1);
                x2p[m] = fmaf(xf, xf, x2p[m]);
            }
    #pragma unroll
    for (int m = 0; m < 2; ++m) {
        x2p[m] += __shfl_xor(x2p[m], 16);
        x2p[m] += __shfl_xor(x2p[m], 32);
    }
    if (q == 0) { x2s[w * 32 + ln] = x2p[0]; x2s[w * 32 + 16 + ln] = x2p[1]; }
    {
        #pragma unroll
        for (int pass = 0; pass < 4; ++pass) {
            const int c_loc = (tid >> 4) + pass * 16;
            const int j4    = (tid & 15) * 4;
            const float4 v = *(const float4*)(embed + (size_t)c_loc * DIM + j4);
            f16x4 h1, h2;
            h1[0] = (_Float16)v.x; h2[0] = (_Float16)(v.x - (float)h1[0]);
            h1[1] = (_Float16)v.y; h2[1] = (_Float16)(v.y - (float)h1[1]);
            h1[2] = (_Float16)v.z; h2[2] = (_Float16)(v.z - (float)h1[2]);
            h1[3] = (_Float16)v.w; h2[3] = (_Float16)(v.w - (float)h1[3]);
            *(f16x4*)(ep + c_loc * EP_ROW + j4)            = h1;
            *(f16x4*)(ep + EP_PLANE + c_loc * EP_ROW + j4) = h2;
        }
    }
    __syncthreads();
    float bs[2][4]; int bi[2][4];
    #pragma unroll
    for (int m = 0; m < 2; ++m)
        #pragma unroll
        for (int r = 0; r < 4; ++r) { bs[m][r] = FLT_MAX; bi[m][r] = 0; }
    for (int kc = 0; kc < 16; ++kc) {
        const int cur = kc & 1, nxt = cur ^ 1;
        float4 ev[4];
        if (kc < 15)
            #pragma unroll
            for (int pass = 0; pass < 4; ++pass) {
                const int c_loc = (tid >> 4) + pass * 16;
                const int j4    = (tid & 15) * 4;
                ev[pass] = *(const float4*)(embed + (size_t)((kc + 1) * 64 + c_loc) * DIM + j4);
            }
        const _Float16* p1 = ep + cur * 2 * EP_PLANE;
        const _Float16* p2 = p1 + EP_PLANE;
        #pragma unroll
        for (int n = 0; n < 4; ++n) {
            const int coff = (n * 16 + ln) * EP_ROW + q * 8;
            const f16x8 b1k0 = *(const f16x8*)(p1 + coff);
            const f16x8 b1k1 = *(const f16x8*)(p1 + coff + 32);
            const f16x8 b2k0 = *(const f16x8*)(p2 + coff);
            const f16x8 b2k1 = *(const f16x8*)(p2 + coff + 32);
            const int   c_lane = kc * 64 + n * 16 + ln;
            const float e2c    = e2s[c_lane];
            #pragma unroll
            for (int m = 0; m < 2; ++m) {
                f32x4 C = {0.f, 0.f, 0.f, 0.f};
                C = __builtin_amdgcn_mfma_f32_16x16x32_f16(af[1][m][0], b2k0, C, 0, 0, 0);
                C = __builtin_amdgcn_mfma_f32_16x16x32_f16(af[1][m][1], b2k1, C, 0, 0, 0);
                C = __builtin_amdgcn_mfma_f32_16x16x32_f16(af[1][m][0], b1k0, C, 0, 0, 0);
                C = __builtin_amdgcn_mfma_f32_16x16x32_f16(af[1][m][1], b1k1, C, 0, 0, 0);
                C = __builtin_amdgcn_mfma_f32_16x16x32_f16(af[0][m][0], b2k0, C, 0, 0, 0);
                C = __builtin_amdgcn_mfma_f32_16x16x32_f16(af[0][m][1], b2k1, C, 0, 0, 0);
                C = __builtin_amdgcn_mfma_f32_16x16x32_f16(af[0][m][0], b1k0, C, 0, 0, 0);
                C = __builtin_amdgcn_mfma_f32_16x16x32_f16(af[0][m][1], b1k1, C, 0, 0, 0);
                #pragma unroll
                for (int r = 0; r < 4; ++r) {
                    const float s = fmaf(-2.f, C[r], e2c);
                    if (s < bs[m][r]) { bs[m][r] = s; bi[m][r] = c_lane; }
                }
            }
        }
        if (kc < 15) {
            _Float16* w1 = ep + nxt * 2 * EP_PLANE;
            _Float16* w2 = w1 + EP_PLANE;
            #pragma unroll
            for (int pass = 0; pass < 4; ++pass) {
                const int c_loc = (tid >> 4) + pass * 16;
                const int j4    = (tid & 15) * 4;
                const float4 v = ev[pass];
                f16x4 h1, h2;
                h1[0] = (_Float16)v.x; h2[0] = (_Float16)(v.x - (float)h1[0]);
                h1[1] = (_Float16)v.y; h2[1] = (_Float16)(v.y - (float)h1[1]);
                h1[2] = (_Float16)v.z; h2[2] = (_Float16)(v.z - (float)h1[2]);
                h1[3] = (_Float16)v.w; h2[3] = (_Float16)(v.w - (float)h1[3]);
                *(f16x4*)(w1 + c_loc * EP_ROW + j4) = h1;
                *(f16x4*)(w2 + c_loc * EP_ROW + j4) = h2;
            }
        }
        __syncthreads();
    }
    float mdloc = 0.f;
    #pragma unroll
    for (int m = 0; m < 2; ++m)
        #pragma unroll
        for (int r = 0; r < 4; ++r) {
            float s = bs[m][r]; int i = bi[m][r];
            #pragma unroll
            for (int mask = 1; mask < 16; mask <<= 1) {
                const float s2 = __shfl_xor(s, mask);
                const int   i2 = __shfl_xor(i, mask);
                if (s2 < s || (s2 == s && i2 < i)) { s = s2; i = i2; }
            }
            if (ln == 0) {
                const int t_loc = w * 32 + m * 16 + q * 4 + r;
                ibest[t_loc] = i;
                out_idx[b * TT + t0 + t_loc] = (float)i;
                atomicAdd(&counts[i], 1.0f);
                mdloc += x2s[t_loc] + s;
            }
        }
    if (ln == 0) atomicAdd(mdsum, mdloc);
    __syncthreads();
    if (tid == 0) atomicAdd(distsum, mdsum[0]);
    #pragma unroll
    for (int p = 0; p < 32; ++p) {
        const int f  = p * 256 + tid;
        const int j  = f >> 7;
        const int tt = f & 127;
        out_q[(size_t)(b * DIM + j) * TT + t0 + tt] =
            embed[(size_t)ibest[tt] * DIM + j];
    }
}

// finalize: in-place counts->avg_probs, perplexity, usage, commitment
__global__ __launch_bounds__(1024) void finalize_kernel(
    float* __restrict__ avg, float* __restrict__ commit_slot,
    float* __restrict__ out_perp, float* __restrict__ out_usage)
{
    __shared__ float s_ent[1024];
    __shared__ float s_use[1024];
    const int k = threadIdx.x;
    const float p = avg[k] * (1.0f / (float)NTOT);
    avg[k] = p;
    s_ent[k] = p * logf(p + 1e-10f);
    s_use[k] = p * logf(p * 1024.f + 1e-10f);
    __syncthreads();
    for (int off = 512; off > 0; off >>= 1) {
        if (k < off) { s_ent[k] += s_ent[k + off]; s_use[k] += s_use[k + off]; }
        __syncthreads();
    }
    if (k == 0) {
        const float ds = commit_slot[0];
        *out_perp      = expf(-s_ent[0]);
        *out_usage     = s_use[0];
        commit_slot[0] = 0.25f * ds * (1.0f / ((float)NTOT * (float)DIM));
    }
}

extern "C" void kernel_launch(void* const* d_in, const int* in_sizes, int n_in,
                              void* d_out, int out_size, void* d_ws, size_t ws_size,
                              hipStream_t stream) {
    const float* x     = (const float*)d_in[0];
    const float* embed = (const float*)d_in[1];

    float* out        = (float*)d_out;
    float* out_q      = out;             // 4194304
    float* out_commit = out + 4194304;   // distsum accumulator first
    float* out_perp   = out + 4194305;
    float* out_avg    = out + 4194306;   // counts accumulator first
    float* out_idx    = out + 4195330;
    // usage at out + 4260866

    if (ws_size >= WS_NEED) {
        _Float16* planes = (_Float16*)d_ws;
        float*    e2g    = (float*)((char*)d_ws + 262144);
        prep_kernel<<<32, 256, 0, stream>>>(embed, planes, e2g, out_avg, out_commit);
        argmin_fused<<<1024, 256, 0, stream>>>(x, planes, e2g, embed,
                                               out_q, out_idx, out_avg, out_commit);
    } else {
        hipMemsetAsync(out_commit, 0, 1026 * sizeof(float), stream);
        argmin_fb<<<512, 256, 0, stream>>>(x, embed, out_q, out_idx, out_avg, out_commit);
    }
    finalize_kernel<<<1, 1024, 0, stream>>>(out_avg, out_commit, out_perp, out + 4260866);
}

// Round 2
// 144.572 us; speedup vs baseline: 1.0335x; 1.0335x over previous
//
#include <hip/hip_runtime.h>
#include <cfloat>
#include <cmath>

#define DIM 64
#define TT 2048
#define NTOT 65536
#define KE 1024

typedef _Float16 f16x8 __attribute__((ext_vector_type(8)));
typedef _Float16 f16x4 __attribute__((ext_vector_type(4)));
typedef float    f32x4 __attribute__((ext_vector_type(4)));

// ws layout (bytes):
//   planes [0, 262144)      : fp16 hi plane (131072 B) + fp16 lo plane (131072 B)
//   e2     [262144, 266240) : 1024 f32
// plane vector layout (B-fragment-ready, verified R5/R6): f16x8 index
//   ((g*2+k)*64 + l) for group g (16 codes), kstep k, lane l=q*16+ln holding
//   embed_plane[c=g*16+ln][j=k*32+q*8 .. +7].
#define WS_NEED 266240

// ============================ fast path ====================================
__global__ __launch_bounds__(256) void prep_kernel(
    const float* __restrict__ embed,
    _Float16* __restrict__ planes,
    float* __restrict__ e2g,
    float* __restrict__ counts,        // out_avg region  (zeroed here)
    float* __restrict__ distsum)       // out_commit slot (zeroed here)
{
    const int gidx = blockIdx.x * 256 + threadIdx.x;   // 8192 threads
    const int g  = gidx >> 7;
    const int k  = (gidx >> 6) & 1;
    const int l  = gidx & 63;
    const int q  = l >> 4;
    const int ln = l & 15;
    const int c  = g * 16 + ln;
    const int jb = k * 32 + q * 8;

    const float4 v0 = *(const float4*)(embed + (size_t)c * DIM + jb);
    const float4 v1 = *(const float4*)(embed + (size_t)c * DIM + jb + 4);
    const float xf[8] = {v0.x, v0.y, v0.z, v0.w, v1.x, v1.y, v1.z, v1.w};
    f16x8 h1, h2;
    #pragma unroll
    for (int e = 0; e < 8; ++e) {
        const _Float16 a = (_Float16)xf[e];
        h1[e] = a;
        h2[e] = (_Float16)(xf[e] - (float)a);   // exact residual
    }
    const int off = ((g * 2 + k) * 64 + l) * 8;
    *(f16x8*)(planes + off)         = h1;
    *(f16x8*)(planes + 65536 + off) = h2;

    if (gidx < KE) {
        const float4* rp = (const float4*)(embed + (size_t)gidx * DIM);
        float s = 0.f;
        #pragma unroll
        for (int i = 0; i < 16; ++i) {
            const float4 v = rp[i];
            s += v.x * v.x + v.y * v.y + v.z * v.z + v.w * v.w;
        }
        e2g[gidx]    = s;
        counts[gidx] = 0.f;
        if (gidx == 0) distsum[0] = 0.f;
    }
}

// Fused full-K argmin + gather. Grid 1024 = one block per 64 t, all 1024
// codes per block (block-local exact argmin -> no keys pass, gather fused).
// R1 post-mortem: LDS staging + per-iteration barrier exposed the vmcnt(0)
// barrier-drain stall (MfmaUtil 28->16%). This version goes back to direct
// L2->register B loads (L2 traffic 512MB/~25us ~ 20TB/s < 34.5 ceiling) but
// breaks the load->use dependency with a 4-buffer distance-2 register
// pipeline. NO barriers in the hot loop; waves run free.
// Numerics identical to verified R1: same planes, same 8-MFMA accumulation
// order (small terms first), strict < + ascending index tie-break.
__global__ __launch_bounds__(256, 4) void argmin_fused(
    const float* __restrict__ x,       // [B][D][T]
    const _Float16* __restrict__ P,    // ws planes (hi at +0, lo at +131072 B)
    const float* __restrict__ e2g,     // ws e2
    const float* __restrict__ embed,
    float* __restrict__ out_q,
    float* __restrict__ out_idx,
    float* __restrict__ counts,
    float* __restrict__ distsum)
{
    __shared__ float e2s[1024];
    __shared__ int   ibest[64];
    __shared__ float x2s[64];
    __shared__ float mdsum[1];

    const int tid = threadIdx.x;
    const int l   = tid & 63;
    const int w   = tid >> 6;
    const int q   = l >> 4;
    const int ln  = l & 15;
    const int n0  = blockIdx.x << 6;   // global t index base
    const int b   = n0 >> 11;          // TT = 2048
    const int t0  = n0 & 2047;

    if (tid == 0) mdsum[0] = 0.f;
    *(float4*)&e2s[tid * 4] = *(const float4*)(e2g + tid * 4);

    // ---- A fragments: fp16 split in registers (layout verified R5/R6) ----
    // t = t0 + w*16 + ln, j = k*32 + q*8 + jj
    f16x8 af[2][2];                    // [plane][k]
    float x2p = 0.f;
    #pragma unroll
    for (int k = 0; k < 2; ++k)
        #pragma unroll
        for (int jj = 0; jj < 8; ++jj) {
            const int j = k * 32 + q * 8 + jj;
            const float xf = x[(size_t)(b * DIM + j) * TT + t0 + w * 16 + ln];
            const _Float16 h1 = (_Float16)xf;
            af[0][k][jj] = h1;
            af[1][k][jj] = (_Float16)(xf - (float)h1);
            x2p = fmaf(xf, xf, x2p);
        }
    // full ||x_t||^2: sum the 4 q-quarters (lanes with same ln)
    x2p += __shfl_xor(x2p, 16);
    x2p += __shfl_xor(x2p, 32);
    if (q == 0) x2s[w * 16 + ln] = x2p;
    __syncthreads();                   // e2s, x2s ready (only pre-loop barrier)

    float bs[4];
    int   bi_[4];
    #pragma unroll
    for (int r = 0; r < 4; ++r) { bs[r] = FLT_MAX; bi_[r] = 0; }

    // B fragments for group gg (f16x8 view, verified R0 indexing):
    //   b1k0 = base[gg*128], b1k1 = base[gg*128+64],
    //   b2k0 = base[gg*128+8192], b2k1 = base[gg*128+8192+64]
    // Overfetch for gg in [64,66) stays inside ws (reads e2 region, unused).
    const f16x8* base = (const f16x8*)P + l;
#define LOADG(buf, gg) do {                                                  \
        const f16x8* gp_ = base + (gg) * 128;                                \
        buf[0] = gp_[0];                                                     \
        buf[1] = gp_[64];                                                    \
        buf[2] = gp_[8192];                                                  \
        buf[3] = gp_[8192 + 64];                                             \
    } while (0)

#define COMPUTE(buf, gg) do {                                                \
        const int   cgl_ = (gg) * 16 + ln;                                   \
        const float e2c_ = e2s[cgl_];                                        \
        f32x4 C = {0.f, 0.f, 0.f, 0.f};                                      \
        /* small terms first for accuracy (verified R5/R6 ordering) */       \
        C = __builtin_amdgcn_mfma_f32_16x16x32_f16(af[1][0], buf[2], C, 0, 0, 0); \
        C = __builtin_amdgcn_mfma_f32_16x16x32_f16(af[1][1], buf[3], C, 0, 0, 0); \
        C = __builtin_amdgcn_mfma_f32_16x16x32_f16(af[1][0], buf[0], C, 0, 0, 0); \
        C = __builtin_amdgcn_mfma_f32_16x16x32_f16(af[1][1], buf[1], C, 0, 0, 0); \
        C = __builtin_amdgcn_mfma_f32_16x16x32_f16(af[0][0], buf[2], C, 0, 0, 0); \
        C = __builtin_amdgcn_mfma_f32_16x16x32_f16(af[0][1], buf[3], C, 0, 0, 0); \
        C = __builtin_amdgcn_mfma_f32_16x16x32_f16(af[0][0], buf[0], C, 0, 0, 0); \
        C = __builtin_amdgcn_mfma_f32_16x16x32_f16(af[0][1], buf[1], C, 0, 0, 0); \
        _Pragma("unroll")                                                    \
        for (int r = 0; r < 4; ++r) {                                        \
            const float s = fmaf(-2.f, C[r], e2c_);                          \
            /* strict < + ascending c keeps lowest index on ties */          \
            if (s < bs[r]) { bs[r] = s; bi_[r] = cgl_; }                     \
        }                                                                    \
    } while (0)

    // ---- hot loop: 64 groups of 16 codes, 4-buffer distance-2 pipeline ----
    f16x8 bA[4], bB[4], bA2[4], bB2[4];
    LOADG(bA, 0);
    LOADG(bB, 1);
    #pragma unroll 1
    for (int g = 0; g < 64; g += 4) {
        LOADG(bA2, g + 2);             // issue 2 phases ahead of use
        LOADG(bB2, g + 3);
        COMPUTE(bA, g);
        COMPUTE(bB, g + 1);
        LOADG(bA, g + 4);              // g=60: gg=64/65 = harmless overfetch
        LOADG(bB, g + 5);
        COMPUTE(bA2, g + 2);
        COMPUTE(bB2, g + 3);
    }
#undef LOADG
#undef COMPUTE

    // ---- reduce over the 16 code-columns; block-local result is final ----
    float mdloc = 0.f;
    #pragma unroll
    for (int r = 0; r < 4; ++r) {
        float s = bs[r]; int i = bi_[r];
        #pragma unroll
        for (int mask = 1; mask < 16; mask <<= 1) {
            const float s2 = __shfl_xor(s, mask);
            const int   i2 = __shfl_xor(i, mask);
            if (s2 < s || (s2 == s && i2 < i)) { s = s2; i = i2; }
        }
        if (ln == 0) {
            const int t_loc = w * 16 + q * 4 + r;   // C-row map (verified)
            ibest[t_loc] = i;
            out_idx[n0 + t_loc] = (float)i;
            atomicAdd(&counts[i], 1.0f);
            mdloc += x2s[t_loc] + s;                // ||x||^2 + e^2 - 2 x.e
        }
    }
    if (ln == 0) atomicAdd(&mdsum[0], mdloc);
    __syncthreads();
    if (tid == 0) atomicAdd(distsum, mdsum[0]);

    // ---- gather: out_q[b][j][t0+tt] = embed[ibest[tt]][j] (embed L2-hot) ---
    #pragma unroll
    for (int p = 0; p < 16; ++p) {
        const int f  = p * 256 + tid;
        const int j  = f >> 6;
        const int tt = f & 63;
        out_q[(size_t)(b * DIM + j) * TT + t0 + tt] =
            embed[(size_t)ibest[tt] * DIM + j];
    }
}

// ======================= fallback path (Round-5, passed) ====================
#define EP_ROW   72
#define EP_PLANE 4608
#define SMEM_BYTES (36864 + 4096 + 512 + 512 + 16)

__global__ __launch_bounds__(256, 2) void argmin_fb(
    const float* __restrict__ x, const float* __restrict__ embed,
    float* __restrict__ out_q, float* __restrict__ out_idx,
    float* __restrict__ counts, float* __restrict__ distsum)
{
    __shared__ __align__(16) char smem[SMEM_BYTES];
    _Float16* ep  = (_Float16*)smem;
    float* e2s    = (float*)(smem + 36864);
    float* x2s    = (float*)(smem + 36864 + 4096);
    int*   ibest  = (int*)  (smem + 36864 + 4608);
    float* mdsum  = (float*)(smem + 36864 + 5120);

    const int tid = threadIdx.x;
    const int l   = tid & 63;
    const int w   = tid >> 6;
    const int q   = l >> 4;
    const int ln  = l & 15;
    const int bid = blockIdx.x;
    const int b   = bid >> 4;
    const int t0  = (bid & 15) << 7;

    if (tid == 0) mdsum[0] = 0.f;
    #pragma unroll
    for (int pass = 0; pass < 4; ++pass) {
        const int c = pass * 256 + tid;
        const float4* rp = (const float4*)(embed + (size_t)c * DIM);
        float s = 0.f;
        #pragma unroll
        for (int i = 0; i < 16; ++i) {
            const float4 v = rp[i];
            s += v.x * v.x + v.y * v.y + v.z * v.z + v.w * v.w;
        }
        e2s[c] = s;
    }
    f16x8 af[2][2][2];
    float x2p[2] = {0.f, 0.f};
    #pragma unroll
    for (int m = 0; m < 2; ++m)
        #pragma unroll
        for (int k = 0; k < 2; ++k)
            #pragma unroll
            for (int jj = 0; jj < 8; ++jj) {
                const int j = k * 32 + q * 8 + jj;
                const float xf = x[(size_t)(b * DIM + j) * TT + t0 + w * 32 + m * 16 + ln];
                const _Float16 h1 = (_Float16)xf;
                af[0][m][k][jj] = h1;
                af[1][m][k][jj] = (_Float16)(xf - (float)h1);
                x2p[m] = fmaf(xf, xf, x2p[m]);
            }
    #pragma unroll
    for (int m = 0; m < 2; ++m) {
        x2p[m] += __shfl_xor(x2p[m], 16);
        x2p[m] += __shfl_xor(x2p[m], 32);
    }
    if (q == 0) { x2s[w * 32 + ln] = x2p[0]; x2s[w * 32 + 16 + ln] = x2p[1]; }
    {
        #pragma unroll
        for (int pass = 0; pass < 4; ++pass) {
            const int c_loc = (tid >> 4) + pass * 16;
            const int j4    = (tid & 15) * 4;
            const float4 v = *(const float4*)(embed + (size_t)c_loc * DIM + j4);
            f16x4 h1, h2;
            h1[0] = (_Float16)v.x; h2[0] = (_Float16)(v.x - (float)h1[0]);
            h1[1] = (_Float16)v.y; h2[1] = (_Float16)(v.y - (float)h1[1]);
            h1[2] = (_Float16)v.z; h2[2] = (_Float16)(v.z - (float)h1[2]);
            h1[3] = (_Float16)v.w; h2[3] = (_Float16)(v.w - (float)h1[3]);
            *(f16x4*)(ep + c_loc * EP_ROW + j4)            = h1;
            *(f16x4*)(ep + EP_PLANE + c_loc * EP_ROW + j4) = h2;
        }
    }
    __syncthreads();
    float bs[2][4]; int bi[2][4];
    #pragma unroll
    for (int m = 0; m < 2; ++m)
        #pragma unroll
        for (int r = 0; r < 4; ++r) { bs[m][r] = FLT_MAX; bi[m][r] = 0; }
    for (int kc = 0; kc < 16; ++kc) {
        const int cur = kc & 1, nxt = cur ^ 1;
        float4 ev[4];
        if (kc < 15)
            #pragma unroll
            for (int pass = 0; pass < 4; ++pass) {
                const int c_loc = (tid >> 4) + pass * 16;
                const int j4    = (tid & 15) * 4;
                ev[pass] = *(const float4*)(embed + (size_t)((kc + 1) * 64 + c_loc) * DIM + j4);
            }
        const _Float16* p1 = ep + cur * 2 * EP_PLANE;
        const _Float16* p2 = p1 + EP_PLANE;
        #pragma unroll
        for (int n = 0; n < 4; ++n) {
            const int coff = (n * 16 + ln) * EP_ROW + q * 8;
            const f16x8 b1k0 = *(const f16x8*)(p1 + coff);
            const f16x8 b1k1 = *(const f16x8*)(p1 + coff + 32);
            const f16x8 b2k0 = *(const f16x8*)(p2 + coff);
            const f16x8 b2k1 = *(const f16x8*)(p2 + coff + 32);
            const int   c_lane = kc * 64 + n * 16 + ln;
            const float e2c    = e2s[c_lane];
            #pragma unroll
            for (int m = 0; m < 2; ++m) {
                f32x4 C = {0.f, 0.f, 0.f, 0.f};
                C = __builtin_amdgcn_mfma_f32_16x16x32_f16(af[1][m][0], b2k0, C, 0, 0, 0);
                C = __builtin_amdgcn_mfma_f32_16x16x32_f16(af[1][m][1], b2k1, C, 0, 0, 0);
                C = __builtin_amdgcn_mfma_f32_16x16x32_f16(af[1][m][0], b1k0, C, 0, 0, 0);
                C = __builtin_amdgcn_mfma_f32_16x16x32_f16(af[1][m][1], b1k1, C, 0, 0, 0);
                C = __builtin_amdgcn_mfma_f32_16x16x32_f16(af[0][m][0], b2k0, C, 0, 0, 0);
                C = __builtin_amdgcn_mfma_f32_16x16x32_f16(af[0][m][1], b2k1, C, 0, 0, 0);
                C = __builtin_amdgcn_mfma_f32_16x16x32_f16(af[0][m][0], b1k0, C, 0, 0, 0);
                C = __builtin_amdgcn_mfma_f32_16x16x32_f16(af[0][m][1], b1k1, C, 0, 0, 0);
                #pragma unroll
                for (int r = 0; r < 4; ++r) {
                    const float s = fmaf(-2.f, C[r], e2c);
                    if (s < bs[m][r]) { bs[m][r] = s; bi[m][r] = c_lane; }
                }
            }
        }
        if (kc < 15) {
            _Float16* w1 = ep + nxt * 2 * EP_PLANE;
            _Float16* w2 = w1 + EP_PLANE;
            #pragma unroll
            for (int pass = 0; pass < 4; ++pass) {
                const int c_loc = (tid >> 4) + pass * 16;
                const int j4    = (tid & 15) * 4;
                const float4 v = ev[pass];
                f16x4 h1, h2;
                h1[0] = (_Float16)v.x; h2[0] = (_Float16)(v.x - (float)h1[0]);
                h1[1] = (_Float16)v.y; h2[1] = (_Float16)(v.y - (float)h1[1]);
                h1[2] = (_Float16)v.z; h2[2] = (_Float16)(v.z - (float)h1[2]);
                h1[3] = (_Float16)v.w; h2[3] = (_Float16)(v.w - (float)h1[3]);
                *(f16x4*)(w1 + c_loc * EP_ROW + j4) = h1;
                *(f16x4*)(w2 + c_loc * EP_ROW + j4) = h2;
            }
        }
        __syncthreads();
    }
    float mdloc = 0.f;
    #pragma unroll
    for (int m = 0; m < 2; ++m)
        #pragma unroll
        for (int r = 0; r < 4; ++r) {
            float s = bs[m][r]; int i = bi[m][r];
            #pragma unroll
            for (int mask = 1; mask < 16; mask <<= 1) {
                const float s2 = __shfl_xor(s, mask);
                const int   i2 = __shfl_xor(i, mask);
                if (s2 < s || (s2 == s && i2 < i)) { s = s2; i = i2; }
            }
            if (ln == 0) {
                const int t_loc = w * 32 + m * 16 + q * 4 + r;
                ibest[t_loc] = i;
                out_idx[b * TT + t0 + t_loc] = (float)i;
                atomicAdd(&counts[i], 1.0f);
                mdloc += x2s[t_loc] + s;
            }
        }
    if (ln == 0) atomicAdd(mdsum, mdloc);
    __syncthreads();
    if (tid == 0) atomicAdd(distsum, mdsum[0]);
    #pragma unroll
    for (int p = 0; p < 32; ++p) {
        const int f  = p * 256 + tid;
        const int j  = f >> 7;
        const int tt = f & 127;
        out_q[(size_t)(b * DIM + j) * TT + t0 + tt] =
            embed[(size_t)ibest[tt] * DIM + j];
    }
}

// finalize: in-place counts->avg_probs, perplexity, usage, commitment
__global__ __launch_bounds__(1024) void finalize_kernel(
    float* __restrict__ avg, float* __restrict__ commit_slot,
    float* __restrict__ out_perp, float* __restrict__ out_usage)
{
    __shared__ float s_ent[1024];
    __shared__ float s_use[1024];
    const int k = threadIdx.x;
    const float p = avg[k] * (1.0f / (float)NTOT);
    avg[k] = p;
    s_ent[k] = p * logf(p + 1e-10f);
    s_use[k] = p * logf(p * 1024.f + 1e-10f);
    __syncthreads();
    for (int off = 512; off > 0; off >>= 1) {
        if (k < off) { s_ent[k] += s_ent[k + off]; s_use[k] += s_use[k + off]; }
        __syncthreads();
    }
    if (k == 0) {
        const float ds = commit_slot[0];
        *out_perp      = expf(-s_ent[0]);
        *out_usage     = s_use[0];
        commit_slot[0] = 0.25f * ds * (1.0f / ((float)NTOT * (float)DIM));
    }
}

extern "C" void kernel_launch(void* const* d_in, const int* in_sizes, int n_in,
                              void* d_out, int out_size, void* d_ws, size_t ws_size,
                              hipStream_t stream) {
    const float* x     = (const float*)d_in[0];
    const float* embed = (const float*)d_in[1];

    float* out        = (float*)d_out;
    float* out_q      = out;             // 4194304
    float* out_commit = out + 4194304;   // distsum accumulator first
    float* out_perp   = out + 4194305;
    float* out_avg    = out + 4194306;   // counts accumulator first
    float* out_idx    = out + 4195330;
    // usage at out + 4260866

    if (ws_size >= WS_NEED) {
        _Float16* planes = (_Float16*)d_ws;
        float*    e2g    = (float*)((char*)d_ws + 262144);
        prep_kernel<<<32, 256, 0, stream>>>(embed, planes, e2g, out_avg, out_commit);
        argmin_fused<<<1024, 256, 0, stream>>>(x, planes, e2g, embed,
                                               out_q, out_idx, out_avg, out_commit);
    } else {
        hipMemsetAsync(out_commit, 0, 1026 * sizeof(float), stream);
        argmin_fb<<<512, 256, 0, stream>>>(x, embed, out_q, out_idx, out_avg, out_commit);
    }
    finalize_kernel<<<1, 1024, 0, stream>>>(out_avg, out_commit, out_perp, out + 4260866);
}